// Round 7
// baseline (130.776 us; speedup 1.0000x reference)
//
#include <hip/hip_runtime.h>
#include <hip/hip_bf16.h>

#define NIMG 4
#define CCH  32
#define PPIX 131072          // 256*512
#define KLBL 16

#define CPB  4                         // channels per k1 block
#define NCG  (CCH / CPB)               // 8 channel-groups
#define K1_CHUNK 8192
#define K1_NCHUNK (PPIX / K1_CHUNK)    // 16
#define K2_CHUNK 1024
#define K2_NCHUNK (PPIX / K2_CHUNK)    // 128

// workspace layout (floats): all plain stores, no zero-init needed
//   mu_part  [NIMG][K1_NCHUNK][NCG][64]   = 32768
//   sumd_part[NIMG*K2_NCHUNK][16]         =  8192
//   cnt_part [NIMG*K2_NCHUNK][16]         =  8192

__device__ __forceinline__ float wave_sum(float v) {
#pragma unroll
    for (int m = 1; m < 64; m <<= 1) v += __shfl_xor(v, m);
    return v;
}

// Kernel 1: per-block partial sums  mu_part[n][chunk][cg][c_in*16+k]
// 4 channels per block; 4x16 register accumulators, fully unrolled indexing.
__global__ __launch_bounds__(256) void k1_mu(const float* __restrict__ feat,
                                             const int* __restrict__ gt,
                                             float* __restrict__ mu_part) {
    int b     = blockIdx.x;
    int chunk = b % K1_NCHUNK;
    int cg    = (b / K1_NCHUNK) % NCG;
    int n     = b / (K1_NCHUNK * NCG);
    int p0    = chunk * K1_CHUNK;
    int tid   = threadIdx.x;

    const float* f0 = feat + ((size_t)(n * CCH + cg * CPB)) * PPIX + p0;
    const float* f1 = f0 + PPIX;
    const float* f2 = f0 + 2 * (size_t)PPIX;
    const float* f3 = f0 + 3 * (size_t)PPIX;
    const int*   g  = gt + (size_t)n * PPIX + p0;

    float acc0[KLBL], acc1[KLBL], acc2[KLBL], acc3[KLBL];
#pragma unroll
    for (int k = 0; k < KLBL; k++) { acc0[k] = 0.f; acc1[k] = 0.f; acc2[k] = 0.f; acc3[k] = 0.f; }

    for (int i = tid * 4; i < K1_CHUNK; i += 256 * 4) {
        float4 a0 = *(const float4*)(f0 + i);
        float4 a1 = *(const float4*)(f1 + i);
        float4 a2 = *(const float4*)(f2 + i);
        float4 a3 = *(const float4*)(f3 + i);
        int4   l  = *(const int4*)(g + i);
#pragma unroll
        for (int k = 0; k < KLBL; k++) {
            float mx = (l.x == k) ? 1.f : 0.f;
            float my = (l.y == k) ? 1.f : 0.f;
            float mz = (l.z == k) ? 1.f : 0.f;
            float mw = (l.w == k) ? 1.f : 0.f;
            acc0[k] = fmaf(a0.x, mx, acc0[k]); acc0[k] = fmaf(a0.y, my, acc0[k]);
            acc0[k] = fmaf(a0.z, mz, acc0[k]); acc0[k] = fmaf(a0.w, mw, acc0[k]);
            acc1[k] = fmaf(a1.x, mx, acc1[k]); acc1[k] = fmaf(a1.y, my, acc1[k]);
            acc1[k] = fmaf(a1.z, mz, acc1[k]); acc1[k] = fmaf(a1.w, mw, acc1[k]);
            acc2[k] = fmaf(a2.x, mx, acc2[k]); acc2[k] = fmaf(a2.y, my, acc2[k]);
            acc2[k] = fmaf(a2.z, mz, acc2[k]); acc2[k] = fmaf(a2.w, mw, acc2[k]);
            acc3[k] = fmaf(a3.x, mx, acc3[k]); acc3[k] = fmaf(a3.y, my, acc3[k]);
            acc3[k] = fmaf(a3.z, mz, acc3[k]); acc3[k] = fmaf(a3.w, mw, acc3[k]);
        }
    }

    __shared__ float warr[4][64];
    int wave = tid >> 6, lane = tid & 63;
#pragma unroll
    for (int k = 0; k < KLBL; k++) {
        float s0 = wave_sum(acc0[k]);
        float s1 = wave_sum(acc1[k]);
        float s2 = wave_sum(acc2[k]);
        float s3 = wave_sum(acc3[k]);
        if (lane == 0) {
            warr[wave][k]      = s0;
            warr[wave][16 + k] = s1;
            warr[wave][32 + k] = s2;
            warr[wave][48 + k] = s3;
        }
    }
    __syncthreads();
    if (tid < 64) {
        float t = warr[0][tid] + warr[1][tid] + warr[2][tid] + warr[3][tid];
        mu_part[(((size_t)n * K1_NCHUNK + chunk) * NCG + cg) * 64 + tid] = t;
    }
}

// Kernel 2: reduce mu partials into LDS, then per-pixel ||f_p - mu[:,gt[p]]||;
// per-block partial sums/counts via plain stores (no atomics).
__global__ __launch_bounds__(256) void k2_var(const float* __restrict__ feat,
                                              const int* __restrict__ gt,
                                              const float* __restrict__ mu_part,
                                              float* __restrict__ sumd_part,
                                              float* __restrict__ cnt_part) {
    __shared__ float lmu[CCH * KLBL];     // [c*16+k]
    int b     = blockIdx.x;
    int chunk = b % K2_NCHUNK;
    int n     = b / K2_NCHUNK;
    int p0    = chunk * K2_CHUNK;
    int tid   = threadIdx.x;
    const float inv_p = 1.0f / (float)PPIX;

    // phase A: mu[e] = (1/P) * sum over 16 chunk-partials; e = c*16+k, e&63 = within-cg
    for (int e = tid; e < CCH * KLBL; e += 256) {
        float s = 0.f;
#pragma unroll
        for (int ch = 0; ch < K1_NCHUNK; ch++)
            s += mu_part[(((size_t)n * K1_NCHUNK + ch) * NCG + (e >> 6)) * 64 + (e & 63)];
        lmu[e] = s * inv_p;
    }
    __syncthreads();

    int p = p0 + tid * 4;
    int4 l = *(const int4*)(gt + (size_t)n * PPIX + p);
    float d2x = 0.f, d2y = 0.f, d2z = 0.f, d2w = 0.f;
    const float* fb = feat + (size_t)n * CCH * PPIX + p;
#pragma unroll 8
    for (int c = 0; c < CCH; c++) {
        float4 f = *(const float4*)(fb + (size_t)c * PPIX);
        float mx = lmu[c * KLBL + l.x];
        float my = lmu[c * KLBL + l.y];
        float mz = lmu[c * KLBL + l.z];
        float mw = lmu[c * KLBL + l.w];
        float ex = f.x - mx, ey = f.y - my, ez = f.z - mz, ew = f.w - mw;
        d2x = fmaf(ex, ex, d2x); d2y = fmaf(ey, ey, d2y);
        d2z = fmaf(ez, ez, d2z); d2w = fmaf(ew, ew, d2w);
    }
    float dx = sqrtf(d2x), dy = sqrtf(d2y), dz = sqrtf(d2z), dw = sqrtf(d2w);

    float s[KLBL], ct[KLBL];
#pragma unroll
    for (int k = 0; k < KLBL; k++) {
        float mx = (l.x == k) ? 1.f : 0.f;
        float my = (l.y == k) ? 1.f : 0.f;
        float mz = (l.z == k) ? 1.f : 0.f;
        float mw = (l.w == k) ? 1.f : 0.f;
        s[k]  = fmaf(dx, mx, fmaf(dy, my, fmaf(dz, mz, dw * mw)));
        ct[k] = mx + my + mz + mw;
    }

    __shared__ float warr[4][32];
    int wave = tid >> 6, lane = tid & 63;
#pragma unroll
    for (int k = 0; k < KLBL; k++) {
        float ssum = wave_sum(s[k]);
        float csum = wave_sum(ct[k]);
        if (lane == 0) { warr[wave][k] = ssum; warr[wave][16 + k] = csum; }
    }
    __syncthreads();
    if (tid < 32) {
        float t = warr[0][tid] + warr[1][tid] + warr[2][tid] + warr[3][tid];
        if (tid < 16) sumd_part[(size_t)b * 16 + tid]        = t;
        else          cnt_part [(size_t)b * 16 + (tid - 16)] = t;
    }
}

// Kernel 3: reduce all partials, compute losses, write out[0..3] + mu (2048).
__global__ __launch_bounds__(256) void k3_final(const float* __restrict__ mu_part,
                                                const float* __restrict__ sumd_part,
                                                const float* __restrict__ cnt_part,
                                                float* __restrict__ out) {
    __shared__ float mu[NIMG * CCH * KLBL];   // [n*512 + c*16 + k]
    __shared__ float sqmu[NIMG * KLBL];
    __shared__ float ps[4][64], pc[4][64];
    int t = threadIdx.x;
    const float inv_p = 1.0f / (float)PPIX;

    for (int m = t; m < NIMG * CCH * KLBL; m += 256) {
        int n = m >> 9, e = m & 511;
        float s = 0.f;
#pragma unroll
        for (int ch = 0; ch < K1_NCHUNK; ch++)
            s += mu_part[(((size_t)n * K1_NCHUNK + ch) * NCG + (e >> 6)) * 64 + (e & 63)];
        float v = s * inv_p;
        mu[m]      = v;
        out[4 + m] = v;
    }
    __syncthreads();

    float sq = 0.f;
    if (t < 64) {
        int n = t >> 4, k = t & 15;
#pragma unroll
        for (int c = 0; c < CCH; c++) {
            float m = mu[n * 512 + c * KLBL + k];
            sq = fmaf(m, m, sq);
        }
        sqmu[t] = sq;
    }
    // partial sumd/cnt reduction: 4 threads per (n,k), 32 chunks each
    {
        int q = t >> 6, nk = t & 63;
        int n2 = nk >> 4, k2 = nk & 15;
        float ss = 0.f, cc = 0.f;
        for (int ch = q * 32; ch < q * 32 + 32; ch++) {
            int idx = (n2 * K2_NCHUNK + ch) * 16 + k2;
            ss += sumd_part[idx];
            cc += cnt_part[idx];
        }
        ps[q][nk] = ss;
        pc[q][nk] = cc;
    }
    __syncthreads();

    if (t < 64) {
        int n = t >> 4, k = t & 15;
        float sumd_t = ps[0][t] + ps[1][t] + ps[2][t] + ps[3][t];
        float cnt_t  = pc[0][t] + pc[1][t] + pc[2][t] + pc[3][t];

        float dsum = 0.f;
#pragma unroll
        for (int j = 0; j < KLBL; j++) {
            if (j == k) continue;
            float gram = 0.f;
#pragma unroll
            for (int c = 0; c < CCH; c++)
                gram = fmaf(mu[n * 512 + c * KLBL + k], mu[n * 512 + c * KLBL + j], gram);
            float sqd = sq + sqmu[n * KLBL + j] - 2.f * gram;
            dsum += (sqd > 0.f) ? sqrtf(sqd) : 0.f;
        }
        float dist_term = fmaxf(2.f * 0.2f - dsum * (1.f / (KLBL - 1)), 0.f);
        float sqm = (sq > 0.f) ? sqrtf(sq) : 0.f;
        float v = (sumd_t + ((float)PPIX - cnt_t) * sqm) * inv_p;
        float var_term = fmaxf(v - 0.2f, 0.f);

        float d_r = wave_sum(dist_term);
        float v_r = wave_sum(var_term);
        float n_r = wave_sum(sqm);
        if (t == 0) {
            float variance_loss      = v_r * (1.f / (NIMG * KLBL));
            float distance_loss      = d_r * (1.f / (NIMG * KLBL));
            float normalization_loss = n_r * (1.f / (NIMG * KLBL));
            out[0] = variance_loss + distance_loss + 0.001f * normalization_loss;
            out[1] = variance_loss;
            out[2] = distance_loss;
            out[3] = normalization_loss;
        }
    }
}

extern "C" void kernel_launch(void* const* d_in, const int* in_sizes, int n_in,
                              void* d_out, int out_size, void* d_ws, size_t ws_size,
                              hipStream_t stream) {
    const float* feat = (const float*)d_in[0];
    const int*   gt   = (const int*)d_in[1];
    float* out       = (float*)d_out;
    float* mu_part   = (float*)d_ws;                                  // 32768 floats
    float* sumd_part = mu_part + NIMG * K1_NCHUNK * NCG * 64;         //  8192 floats
    float* cnt_part  = sumd_part + NIMG * K2_NCHUNK * 16;             //  8192 floats

    k1_mu<<<NIMG * NCG * K1_NCHUNK, 256, 0, stream>>>(feat, gt, mu_part);
    k2_var<<<NIMG * K2_NCHUNK, 256, 0, stream>>>(feat, gt, mu_part, sumd_part, cnt_part);
    k3_final<<<1, 256, 0, stream>>>(mu_part, sumd_part, cnt_part, out);
}